// Round 5
// baseline (135.007 us; speedup 1.0000x reference)
//
#include <hip/hip_runtime.h>

// FWHT of 2^24 float32, output scaled by 1/2^24.
// Two passes over global memory:
//   Pass 1: bits 0-13 (contiguous 16K chunks, 64 KB LDS, reg-blocked 5+5+4)
//   Pass 2: bits 14-23 over the (r=1024, c=16384) view. v3: 64-column tiles
//           (256 B global segments; R3 measured 64 B segs at 2.85 TB/s, 128 B
//           in v2 was a big step — continuing the granularity curve).
//           1024 threads, 64 KB LDS, A->B exchange in four 256-row quarters.
//           In-place on d_out, applies 1/N.

#define N_LOG2 24
#define CHUNK_LOG2 14           // pass-1 chunk = 16384 elements = 64 KB LDS
#define CHUNK (1 << CHUNK_LOG2)

// Pass-1 LDS swizzle: flips addr bits 2-4 with (row ^ row>>2)&7, row = e>>5.
// All pass-1 LDS phases land at <=2 lanes/bank (free per m136); keeps 16 B
// alignment for float4 stores.
static __device__ __forceinline__ int swz(int e) {
  return e ^ ((((e >> 5) ^ (e >> 7)) & 7) << 2);
}

static __device__ __forceinline__ void fwht32(float* v) {
#pragma unroll
  for (int h = 1; h < 32; h <<= 1) {
#pragma unroll
    for (int g = 0; g < 32; g += 2 * h) {
#pragma unroll
      for (int k = 0; k < h; ++k) {
        float a = v[g + k], b = v[g + k + h];
        v[g + k] = a + b;
        v[g + k + h] = a - b;
      }
    }
  }
}

static __device__ __forceinline__ void fwht16(float* v) {
#pragma unroll
  for (int h = 1; h < 16; h <<= 1) {
#pragma unroll
    for (int g = 0; g < 16; g += 2 * h) {
#pragma unroll
      for (int k = 0; k < h; ++k) {
        float a = v[g + k], b = v[g + k + h];
        v[g + k] = a + b;
        v[g + k + h] = a - b;
      }
    }
  }
}

// Pass 1: per-block contiguous chunk of 16384 floats; stages over bits 0-13.
// Global I/O: 1 KB/wave-instr loads (float4), 256 B/wave-instr stores.
__global__ __launch_bounds__(512) void fwht_pass1(const float* __restrict__ in,
                                                  float* __restrict__ out) {
  __shared__ float lds[CHUNK];
  const int t = threadIdx.x;                 // [0, 512)
  const int base = (int)blockIdx.x << CHUNK_LOG2;
  float v[32];

  // Group 0: thread owns contiguous e = 32t .. 32t+31 (bits 0-4).
  const float4* g4 = reinterpret_cast<const float4*>(in + base) + t * 8;
#pragma unroll
  for (int q = 0; q < 8; ++q) {
    float4 f = g4[q];
    v[4 * q + 0] = f.x; v[4 * q + 1] = f.y;
    v[4 * q + 2] = f.z; v[4 * q + 3] = f.w;
  }
  fwht32(v);  // bits 0-4
#pragma unroll
  for (int q = 0; q < 8; ++q) {
    int e = t * 32 + q * 4;
    *reinterpret_cast<float4*>(&lds[swz(e)]) =
        make_float4(v[4 * q], v[4 * q + 1], v[4 * q + 2], v[4 * q + 3]);
  }
  __syncthreads();

  // Group 1: thread owns e = lo + (j<<5) + (hi<<10), j = 0..31 (bits 5-9).
  const int lo = t & 31, hi = t >> 5;        // hi in [0,16)
#pragma unroll
  for (int j = 0; j < 32; ++j) v[j] = lds[swz(lo + (j << 5) + (hi << 10))];
  fwht32(v);  // bits 5-9
#pragma unroll
  for (int j = 0; j < 32; ++j) lds[swz(lo + (j << 5) + (hi << 10))] = v[j];
  __syncthreads();

  // Group 2: thread owns e = f + (jr<<10) for f = t, t+512 (bits 10-13).
#pragma unroll
  for (int b = 0; b < 2; ++b) {
    int f = t + (b << 9);
#pragma unroll
    for (int jr = 0; jr < 16; ++jr) v[b * 16 + jr] = lds[swz(f + (jr << 10))];
  }
  fwht16(v);
  fwht16(v + 16);
#pragma unroll
  for (int b = 0; b < 2; ++b) {
    int f = t + (b << 9);
#pragma unroll
    for (int jr = 0; jr < 16; ++jr) out[base + f + (jr << 10)] = v[b * 16 + jr];
  }
}

// Pass 2 v3: view i = r*16384 + c, r in [0,1024), c in [0,16384).
// Block owns a 1024-row x 64-col tile (grid 256, 1024 threads). Every global
// load/store instruction: one row x 64 lanes x 4 B = 256 B contiguous.
// Thread t: c = t&63, rg = t>>6 in [0,16).
//   A phase: v0[j] = row rg+16j (r bits 4-8 via j), v1[j] = row 512+rg+16j.
//   B phase: u0[j] = row (j&15)+16rg+((j>>4)<<9), u1 = +256. fwht32 over j
//            butterflies r bits {0,1,2,3,9}. A+B = r bits 0-9 = global 14-23.
// Exchange via 64 KB LDS in four 256-row quarters (local row = r mod 256;
// both write idx (rg+16j')*64+c and read idx (k+16rg)*64+c are 64 consecutive
// floats per wave instr -> 2 lanes/bank, free).
// In-place safe: loads all precede first barrier, stores follow last one,
// blocks own disjoint column ranges.
__global__ __launch_bounds__(1024, 4) void fwht_pass2(float* __restrict__ io) {
  __shared__ float lds[CHUNK];               // 16384 floats = 64 KB
  const int t = threadIdx.x;                 // [0, 1024)
  const int c = t & 63, rg = t >> 6;         // rg in [0,16)
  const int cbase = (int)blockIdx.x * 64;
  float v0[32], v1[32], u0[32], u1[32];

  // A: load + fwht over r bits 4-8 in each 512-row half.
#pragma unroll
  for (int j = 0; j < 32; ++j)
    v0[j] = io[(rg + 16 * j) * CHUNK + cbase + c];
#pragma unroll
  for (int j = 0; j < 32; ++j)
    v1[j] = io[(512 + rg + 16 * j) * CHUNK + cbase + c];
  fwht32(v0);
  fwht32(v1);

  // Quarter 0: rows [0,256) = v0[j], j in [0,16). Supplies u0[0:16).
#pragma unroll
  for (int j = 0; j < 16; ++j) lds[(rg + 16 * j) * 64 + c] = v0[j];
  __syncthreads();
#pragma unroll
  for (int k = 0; k < 16; ++k) u0[k] = lds[(k + 16 * rg) * 64 + c];
  __syncthreads();

  // Quarter 1: rows [256,512) = v0[j], j in [16,32). Supplies u1[0:16).
#pragma unroll
  for (int j = 16; j < 32; ++j) lds[(rg + 16 * j - 256) * 64 + c] = v0[j];
  __syncthreads();
#pragma unroll
  for (int k = 0; k < 16; ++k) u1[k] = lds[(k + 16 * rg) * 64 + c];
  __syncthreads();

  // Quarter 2: rows [512,768) = v1[j], j in [0,16). Supplies u0[16:32).
#pragma unroll
  for (int j = 0; j < 16; ++j) lds[(rg + 16 * j) * 64 + c] = v1[j];
  __syncthreads();
#pragma unroll
  for (int k = 0; k < 16; ++k) u0[16 + k] = lds[(k + 16 * rg) * 64 + c];
  __syncthreads();

  // Quarter 3: rows [768,1024) = v1[j], j in [16,32). Supplies u1[16:32).
#pragma unroll
  for (int j = 16; j < 32; ++j) lds[(rg + 16 * j - 256) * 64 + c] = v1[j];
  __syncthreads();
#pragma unroll
  for (int k = 0; k < 16; ++k) u1[16 + k] = lds[(k + 16 * rg) * 64 + c];

  // B: fwht over r bits {0,1,2,3,9}; then scale + store.
  fwht32(u0);
  fwht32(u1);
  const float s = 1.0f / 16777216.0f;
#pragma unroll
  for (int j = 0; j < 32; ++j)
    io[(((j & 15) + 16 * rg + ((j >> 4) << 9))) * CHUNK + cbase + c] = u0[j] * s;
#pragma unroll
  for (int j = 0; j < 32; ++j)
    io[((256 + (j & 15) + 16 * rg + ((j >> 4) << 9))) * CHUNK + cbase + c] = u1[j] * s;
}

extern "C" void kernel_launch(void* const* d_in, const int* in_sizes, int n_in,
                              void* d_out, int out_size, void* d_ws, size_t ws_size,
                              hipStream_t stream) {
  const float* in = (const float*)d_in[0];
  float* out = (float*)d_out;
  // N = 2^24: pass 1 -> d_out, pass 2 in-place on d_out.
  fwht_pass1<<<1024, 512, 0, stream>>>(in, out);
  fwht_pass2<<<256, 1024, 0, stream>>>(out);
}